// Round 2
// baseline (36480.060 us; speedup 1.0000x reference)
//
#include <hip/hip_runtime.h>
#include <hip/hip_bf16.h>
#include <stdint.h>

#define SEQ   512
#define NBLK  256

typedef __bf16 bf16_t;
typedef bf16_t bf16x8 __attribute__((ext_vector_type(8)));
typedef bf16_t bf16x4v __attribute__((ext_vector_type(4)));
typedef float  f32x4  __attribute__((ext_vector_type(4)));

// ---- dynamic LDS layout (bytes) ----
#define OFF_WT4   0        // W_in^T packed f32 [8][512][4]  (64 KiB) k=31 col is wy
#define OFF_BIN   65536    // b_in f32[512]
#define OFF_BGT   67584    // b_gate for this block's 4x32 j's
#define OFF_WOUT  68096    // W_out[nb*32..+32]
#define OFF_XS    68224    // xs f32[8][32]; col 31 = y_prev
#define OFF_UNION 69632    // union{ As0[128][64]bf16 + As1[128][64]bf16 (32 KiB) | Gs f32[2][64][129] (64.5 KiB) }
#define SMEM_BYTES 135680
#define GSPLANE   8256     // floats per Gs plane (64*129)

__device__ __forceinline__ void gload16(const void* g, void* lds) {
    __builtin_amdgcn_global_load_lds(
        (const __attribute__((address_space(1))) void*)g,
        (__attribute__((address_space(3))) void*)lds, 16, 0, 0);
}
__device__ __forceinline__ float sigmoid_f(float x) { return 1.f / (1.f + __expf(-x)); }
__device__ __forceinline__ float tanh_f(float x)    { float e = __expf(2.f * x); return 1.f - 2.f / (e + 1.f); }

// two-level grid barrier: 16 leaf counters (128 B apart) + root at ctrs[512].
// release on arrive / acquire on spin gives cross-XCD visibility (agent scope).
__device__ __forceinline__ void grid_sync(int* ctrs, int bid, int gen) {
    __syncthreads();
    if (threadIdx.x == 0) {
        __threadfence();
        int prev = __hip_atomic_fetch_add(ctrs + (bid >> 4) * 32, 1,
                                          __ATOMIC_RELEASE, __HIP_MEMORY_SCOPE_AGENT);
        if (((prev + 1) & 15) == 0)
            __hip_atomic_fetch_add(ctrs + 512, 1, __ATOMIC_RELEASE, __HIP_MEMORY_SCOPE_AGENT);
        while (__hip_atomic_load(ctrs + 512, __ATOMIC_ACQUIRE, __HIP_MEMORY_SCOPE_AGENT) < gen * 16)
            __builtin_amdgcn_s_sleep(1);
        __threadfence();
    }
    __syncthreads();
}

// ---------------- prep kernels ----------------
__global__ void prep_w(const float* __restrict__ W_ih, const float* __restrict__ W_hh,
                       bf16_t* __restrict__ Wcat) {
    const int j = blockIdx.x;
    for (int k = threadIdx.x; k < 1024; k += 256) {
        float v = (k < 512) ? W_ih[(size_t)j * 512 + k] : W_hh[(size_t)j * 512 + (k - 512)];
        Wcat[(size_t)j * 1024 + k] = (bf16_t)v;
    }
}
__global__ void prep_h0(const float* __restrict__ h0, bf16_t* __restrict__ H0) {
    const int b = blockIdx.x;
    for (int d = threadIdx.x; d < 512; d += 256)
        H0[(size_t)b * 512 + d] = (bf16_t)h0[(size_t)b * 512 + d];
}
__global__ void prep_bias(const float* __restrict__ b_ih, const float* __restrict__ b_hh,
                          float* __restrict__ bg, int* __restrict__ ctrs) {
    int j = blockIdx.x * 256 + threadIdx.x;
    bg[j] = b_ih[j] + b_hh[j];
    if (j < 544) ctrs[j] = 0;
}

// ---------------- persistent whole-sequence kernel ----------------
// grid 256 = 16 mb x 16 nb; block 512 thr = 8 waves = (K-half wsl) x (gate wn).
// Weights: register-resident B-fragments (wave: 16 cols x its 512-K half = 128 VGPRs).
// c state: register-resident (8 f32/thread). 2 grid barriers per step.
__global__ __launch_bounds__(512, 2) void holstm_persist(
    const float* __restrict__ x,     const float* __restrict__ y0,
    const float* __restrict__ c0,    const float* __restrict__ W_in,
    const float* __restrict__ b_in,  const float* __restrict__ b_out,
    const float* __restrict__ W_out, const bf16_t* __restrict__ Wcat,
    const float* __restrict__ bgate, bf16_t* __restrict__ X0g,
    bf16_t* __restrict__ Hb0,        bf16_t* __restrict__ Hb1,
    float* __restrict__ out,         int* __restrict__ ctrs)
{
    extern __shared__ char smem[];
    float* WT4  = (float*)(smem + OFF_WT4);
    float* BIN  = (float*)(smem + OFF_BIN);
    float* BGT  = (float*)(smem + OFF_BGT);
    float* WOUT = (float*)(smem + OFF_WOUT);
    float* XS   = (float*)(smem + OFF_XS);
    char*  UNI  = smem + OFF_UNION;
    float* GS   = (float*)UNI;

    const int tid = threadIdx.x;
    const int l   = tid & 63;
    const int w   = tid >> 6;
    const int r   = l & 15;
    const int q   = l >> 4;
    const int wn  = w & 3;      // gate strip (N=32)
    const int wsl = w >> 2;     // K-half select
    const int bid = blockIdx.x;
    const int mb  = bid >> 4;
    const int nb  = bid & 15;

    // one-time LDS staging (coalesced global reads)
    for (int i = tid; i < 16384; i += 512) {
        int k = i & 31, d = i >> 5;
        WT4[(k >> 2) * 2048 + d * 4 + (k & 3)] = W_in[i];
    }
    BIN[tid] = b_in[tid];
    if (tid < 128) BGT[tid]  = bgate[(tid >> 5) * 512 + nb * 32 + (tid & 31)];
    if (tid < 32)  WOUT[tid] = W_out[nb * 32 + tid];

    // one-time register weight fragments: lane l holds W[j][k..k+8)
    bf16x8 wfrag[16][2];
#pragma unroll
    for (int c = 0; c < 16; ++c)
#pragma unroll
        for (int ni = 0; ni < 2; ++ni) {
            const int j = wn * 512 + nb * 32 + ni * 16 + r;
            const int k = wsl * 512 + c * 32 + q * 8;
            wfrag[c][ni] = *(const bf16x8*)(Wcat + (size_t)j * 1024 + k);
        }

    // persistent cell state
    const int erow = tid >> 3, edg = tid & 7;
    float creg[2][4];
#pragma unroll
    for (int h = 0; h < 2; ++h) {
        const int bg2 = mb * 128 + h * 64 + erow;
#pragma unroll
        for (int ii = 0; ii < 4; ++ii)
            creg[h][ii] = c0[(size_t)bg2 * 512 + nb * 32 + edg * 4 + ii];
    }
    const float bout0 = b_out[0];
    __syncthreads();

    for (int t = 0; t < SEQ; ++t) {
        const bf16_t* Hin  = (t & 1) ? Hb1 : Hb0;
        bf16_t*       Hout = (t & 1) ? Hb0 : Hb1;
        const float*  xt   = x + (size_t)t * (2048 * 31);
        const float*  ysrc = t ? (out + (size_t)(t - 1) * 2048) : y0;
        float*        yt   = out + (size_t)t * 2048;

        // ---- stage1: X0 rows [bid*8, +8) = relu([x_t,y] @ W_in^T + b_in) ----
        if (tid < 248) {
            int rr2 = tid / 31, cc = tid - rr2 * 31;
            XS[rr2 * 32 + cc] = xt[(size_t)(bid * 8 + rr2) * 31 + cc];
        } else if (tid < 256) {
            int rr2 = tid - 248;
            XS[rr2 * 32 + 31] = ysrc[bid * 8 + rr2];
            yt[bid * 8 + rr2] = bout0;           // init y output with bias
        }
        __syncthreads();
        {
            const int d = tid;
            const float bi = BIN[d];
            float a0[8];
#pragma unroll
            for (int rr2 = 0; rr2 < 8; ++rr2) a0[rr2] = bi;
#pragma unroll
            for (int k4 = 0; k4 < 8; ++k4) {
                const f32x4 w4 = *(const f32x4*)&WT4[k4 * 2048 + d * 4];
#pragma unroll
                for (int rr2 = 0; rr2 < 8; ++rr2) {
                    const f32x4 x4 = *(const f32x4*)&XS[rr2 * 32 + k4 * 4];
                    a0[rr2] += x4[0] * w4[0] + x4[1] * w4[1] + x4[2] * w4[2] + x4[3] * w4[3];
                }
            }
#pragma unroll
            for (int rr2 = 0; rr2 < 8; ++rr2)
                X0g[(size_t)(bid * 8 + rr2) * 512 + d] = (bf16_t)fmaxf(a0[rr2], 0.f);
        }
        grid_sync(ctrs, bid, 2 * t + 1);

        // ---- stage2: gates GEMM (register-B, LDS-A with XOR swizzle) ----
        f32x4 acc[8][2];
#pragma unroll
        for (int mi = 0; mi < 8; ++mi)
#pragma unroll
            for (int ni = 0; ni < 2; ++ni) {
                f32x4 z = {0.f, 0.f, 0.f, 0.f};
                acc[mi][ni] = z;
            }
        const char* ASw = UNI + (wsl ? 16384 : 0);
#pragma unroll
        for (int kt = 0; kt < 8; ++kt) {
            const int lc = (l & 7) ^ ((l >> 3) & 7);
#pragma unroll
            for (int i = 0; i < 2; ++i) {
                const int rowl = i * 64 + w * 8 + (l >> 3);
                const size_t go = (size_t)(mb * 128 + rowl) * 512 + kt * 64 + lc * 8;
                gload16(X0g + go, UNI + i * 8192 + w * 1024);            // As0 <- X0 half
                gload16(Hin + go, UNI + 16384 + i * 8192 + w * 1024);    // As1 <- H half
            }
            __syncthreads();
#pragma unroll
            for (int c2 = 0; c2 < 2; ++c2) {
                bf16x8 af[8];
#pragma unroll
                for (int mi = 0; mi < 8; ++mi) {
                    const int row = mi * 16 + r;
                    const int ph  = (c2 * 4 + q) ^ (r & 7);
                    af[mi] = *(const bf16x8*)(ASw + row * 128 + ph * 16);
                }
#pragma unroll
                for (int mi = 0; mi < 8; ++mi)
#pragma unroll
                    for (int ni = 0; ni < 2; ++ni)
                        acc[mi][ni] = __builtin_amdgcn_mfma_f32_16x16x32_bf16(
                            af[mi], wfrag[kt * 2 + c2][ni], acc[mi][ni], 0, 0, 0);
            }
            __syncthreads();
        }

        // ---- epilogue: K-half reduction through LDS + fused LSTM cell ----
#pragma unroll
        for (int h = 0; h < 2; ++h) {
#pragma unroll
            for (int mi4 = 0; mi4 < 4; ++mi4) {
                const int mi = h * 4 + mi4;
#pragma unroll
                for (int ni = 0; ni < 2; ++ni)
#pragma unroll
                    for (int rr = 0; rr < 4; ++rr)
                        GS[wsl * GSPLANE + (mi4 * 16 + q * 4 + rr) * 129 + wn * 32 + ni * 16 + r]
                            = acc[mi][ni][rr];
            }
            __syncthreads();
            {
                const int bg2 = mb * 128 + h * 64 + erow;
                const float* g0 = GS + erow * 129;
                const float* g1 = GS + GSPLANE + erow * 129;
                float ysum = 0.f;
                bf16x4v hv;
#pragma unroll
                for (int ii = 0; ii < 4; ++ii) {
                    const int dl = edg * 4 + ii;
                    const float gi = g0[dl]      + g1[dl]      + BGT[dl];
                    const float gf = g0[32 + dl] + g1[32 + dl] + BGT[32 + dl];
                    const float gg = g0[64 + dl] + g1[64 + dl] + BGT[64 + dl];
                    const float go = g0[96 + dl] + g1[96 + dl] + BGT[96 + dl];
                    const float cn = sigmoid_f(gf) * creg[h][ii] + sigmoid_f(gi) * tanh_f(gg);
                    creg[h][ii] = cn;
                    const float hval = sigmoid_f(go) * tanh_f(cn);
                    hv[ii] = (bf16_t)hval;
                    ysum += hval * WOUT[dl];
                }
                *(bf16x4v*)(Hout + (size_t)bg2 * 512 + nb * 32 + edg * 4) = hv;
                ysum += __shfl_xor(ysum, 1);
                ysum += __shfl_xor(ysum, 2);
                ysum += __shfl_xor(ysum, 4);
                if (edg == 0) atomicAdd(yt + bg2, ysum);
            }
            __syncthreads();
        }
        grid_sync(ctrs, bid, 2 * t + 2);
    }
}

// ---------------------------------------------------------------------------
extern "C" void kernel_launch(void* const* d_in, const int* in_sizes, int n_in,
                              void* d_out, int out_size, void* d_ws, size_t ws_size,
                              hipStream_t stream) {
    const float* x     = (const float*)d_in[0];
    const float* h0    = (const float*)d_in[1];
    const float* c0    = (const float*)d_in[2];
    const float* y0    = (const float*)d_in[3];
    const float* W_in  = (const float*)d_in[4];
    const float* b_in  = (const float*)d_in[5];
    const float* W_ih  = (const float*)d_in[6];
    const float* W_hh  = (const float*)d_in[7];
    const float* b_ih  = (const float*)d_in[8];
    const float* b_hh  = (const float*)d_in[9];
    const float* W_out = (const float*)d_in[10];
    const float* b_out = (const float*)d_in[11];
    float* out = (float*)d_out;

    char* ws = (char*)d_ws;
    bf16_t* Wcat  = (bf16_t*)(ws);                  // 4 MiB
    bf16_t* X0    = (bf16_t*)(ws + (4u << 20));     // 2 MiB
    bf16_t* Hb0   = (bf16_t*)(ws + (6u << 20));     // 2 MiB
    bf16_t* Hb1   = (bf16_t*)(ws + (8u << 20));     // 2 MiB
    float*  bgate = (float*)(ws + (10u << 20));     // 8 KiB
    int*    ctrs  = (int*)(ws + (10u << 20) + 8192);// 544 ints

    prep_w   <<<2048, 256, 0, stream>>>(W_ih, W_hh, Wcat);
    prep_h0  <<<2048, 256, 0, stream>>>(h0, Hb0);
    prep_bias<<<8,    256, 0, stream>>>(b_ih, b_hh, bgate, ctrs);

    hipFuncSetAttribute((const void*)holstm_persist,
                        hipFuncAttributeMaxDynamicSharedMemorySize, SMEM_BYTES);
    void* kargs[] = {
        (void*)&x, (void*)&y0, (void*)&c0, (void*)&W_in, (void*)&b_in, (void*)&b_out,
        (void*)&W_out, (void*)&Wcat, (void*)&bgate, (void*)&X0, (void*)&Hb0, (void*)&Hb1,
        (void*)&out, (void*)&ctrs };
    hipError_t e = hipLaunchCooperativeKernel((const void*)holstm_persist,
                                              dim3(NBLK), dim3(512), kargs,
                                              SMEM_BYTES, stream);
    if (e != hipSuccess) {
        // co-residency fallback: 256 blocks x 1 block/CU on 256 CUs
        holstm_persist<<<NBLK, 512, SMEM_BYTES, stream>>>(
            x, y0, c0, W_in, b_in, b_out, W_out, Wcat, bgate, X0, Hb0, Hb1, out, ctrs);
    }
    (void)in_sizes; (void)n_in; (void)out_size; (void)ws_size;
}

// Round 3
// 31814.615 us; speedup vs baseline: 1.1466x; 1.1466x over previous
//
#include <hip/hip_runtime.h>
#include <hip/hip_bf16.h>
#include <stdint.h>

#define SEQ   512
#define NBLK  256

typedef __bf16 bf16_t;
typedef bf16_t bf16x8 __attribute__((ext_vector_type(8)));
typedef bf16_t bf16x4v __attribute__((ext_vector_type(4)));
typedef float  f32x4  __attribute__((ext_vector_type(4)));

// ---- dynamic LDS layout (bytes) ----
#define OFF_WT4   0        // W_in^T packed f32 [8][512][4] (64 KiB)
#define OFF_BIN   65536    // b_in f32[512]
#define OFF_BGT   67584    // b_gate strips for this member (4x32)
#define OFF_WOUT  68096    // W_out[m*32..+32]
#define OFF_XS    68224    // xs f32[8][32]; col 31 = y_prev
#define OFF_UNION 69632    // union{ As0+As1 (32 KiB) | Gs f32[2][64][129] (66 KiB) }
#define SMEM_BYTES 135680
#define GSPLANE   8256     // floats per Gs plane (64*129)

__device__ __forceinline__ void gload16(const void* g, void* lds) {
    __builtin_amdgcn_global_load_lds(
        (const __attribute__((address_space(1))) void*)g,
        (__attribute__((address_space(3))) void*)lds, 16, 0, 0);
}
__device__ __forceinline__ float sigmoid_f(float x) { return 1.f / (1.f + __expf(-x)); }
__device__ __forceinline__ float tanh_f(float x)    { float e = __expf(2.f * x); return 1.f - 2.f / (e + 1.f); }

// group-local (16-block) split barrier; one counter per group, own 128B line
__device__ __forceinline__ void bar_arrive(int* c) {
    __syncthreads();
    if (threadIdx.x == 0) {
        __threadfence();
        __hip_atomic_fetch_add(c, 1, __ATOMIC_RELEASE, __HIP_MEMORY_SCOPE_AGENT);
    }
}
__device__ __forceinline__ void bar_wait(int* c, int target) {
    if (threadIdx.x == 0) {
        while (__hip_atomic_load(c, __ATOMIC_ACQUIRE, __HIP_MEMORY_SCOPE_AGENT) < target)
            __builtin_amdgcn_s_sleep(1);
        __threadfence();
    }
    __syncthreads();
}

// ---------------- prep kernels ----------------
__global__ void prep_w(const float* __restrict__ W_ih, const float* __restrict__ W_hh,
                       bf16_t* __restrict__ Wcat) {
    const int j = blockIdx.x;
    for (int k = threadIdx.x; k < 1024; k += 256) {
        float v = (k < 512) ? W_ih[(size_t)j * 512 + k] : W_hh[(size_t)j * 512 + (k - 512)];
        Wcat[(size_t)j * 1024 + k] = (bf16_t)v;
    }
}
__global__ void prep_h0(const float* __restrict__ h0, bf16_t* __restrict__ H0) {
    const int b = blockIdx.x;
    for (int d = threadIdx.x; d < 512; d += 256)
        H0[(size_t)b * 512 + d] = (bf16_t)h0[(size_t)b * 512 + d];
}
__global__ void prep_bias(const float* __restrict__ b_ih, const float* __restrict__ b_hh,
                          float* __restrict__ bg, int* __restrict__ ctrs) {
    int j = blockIdx.x * 256 + threadIdx.x;
    bg[j] = b_ih[j] + b_hh[j];
    if (j < 544) ctrs[j] = 0;
}

// ---------------- persistent whole-sequence kernel (XCD-local groups) ------
// group G = bid&15 owns batch rows [G*128,+128); member m = bid>>4 owns
// d-strip [m*32,+32) x 4 gates. With bid%8 XCD round-robin, a group's 16
// members share one XCD -> per-step X0/H/y traffic stays in that XCD's L2.
__global__ __launch_bounds__(512, 2) void holstm_persist(
    const float* __restrict__ x,     const float* __restrict__ y0,
    const float* __restrict__ c0,    const float* __restrict__ W_in,
    const float* __restrict__ b_in,  const float* __restrict__ b_out,
    const float* __restrict__ W_out, const bf16_t* __restrict__ Wcat,
    const float* __restrict__ bgate, bf16_t* __restrict__ X0g,
    bf16_t* __restrict__ Hb0,        bf16_t* __restrict__ Hb1,
    float* __restrict__ out,         int* __restrict__ ctrs)
{
    extern __shared__ char smem[];
    float* WT4  = (float*)(smem + OFF_WT4);
    float* BIN  = (float*)(smem + OFF_BIN);
    float* BGT  = (float*)(smem + OFF_BGT);
    float* WOUT = (float*)(smem + OFF_WOUT);
    float* XS   = (float*)(smem + OFF_XS);
    char*  UNI  = smem + OFF_UNION;
    float* GS   = (float*)UNI;

    const int tid = threadIdx.x;
    const int l   = tid & 63;
    const int w   = tid >> 6;
    const int r   = l & 15;
    const int q   = l >> 4;
    const int wn  = w & 3;       // gate strip
    const int wsl = w >> 2;      // K-half select
    const int bid = blockIdx.x;
    const int G   = bid & 15;    // group (batch slice), fixed XCD (bid%8 heuristic)
    const int m   = bid >> 4;    // member (d-strip)
    int* gctr = ctrs + G * 32;

    // one-time LDS staging
    for (int i = tid; i < 16384; i += 512) {
        int k = i & 31, d = i >> 5;
        WT4[(k >> 2) * 2048 + d * 4 + (k & 3)] = W_in[i];
    }
    BIN[tid] = b_in[tid];
    if (tid < 128) BGT[tid]  = bgate[(tid >> 5) * 512 + m * 32 + (tid & 31)];
    if (tid < 32)  WOUT[tid] = W_out[m * 32 + tid];

    // one-time register weight fragments: N=32 cols (ni*16+r), K-half wsl
    bf16x8 wfrag[16][2];
#pragma unroll
    for (int c = 0; c < 16; ++c)
#pragma unroll
        for (int ni = 0; ni < 2; ++ni) {
            const int j = wn * 512 + m * 32 + ni * 16 + r;
            const int k = wsl * 512 + c * 32 + q * 8;
            wfrag[c][ni] = *(const bf16x8*)(Wcat + (size_t)j * 1024 + k);
        }

    // persistent cell state (registers)
    const int erow = tid >> 3, edg = tid & 7;
    float creg[2][4];
#pragma unroll
    for (int h = 0; h < 2; ++h) {
        const int bg2 = G * 128 + h * 64 + erow;
#pragma unroll
        for (int ii = 0; ii < 4; ++ii)
            creg[h][ii] = c0[(size_t)bg2 * 512 + m * 32 + edg * 4 + ii];
    }
    const float bout0 = b_out[0];
    const int rowbase = G * 128 + m * 8;       // this member's stage-1 rows
    const int xr = tid / 31, xc = tid - xr * 31;

    // prefetch x for t=0
    float xreg = 0.f;
    if (tid < 248)
        xreg = x[(size_t)(rowbase + xr) * 31 + xc];
    __syncthreads();

    for (int t = 0; t < SEQ; ++t) {
        const bf16_t* Hin  = (t & 1) ? Hb1 : Hb0;
        bf16_t*       Hout = (t & 1) ? Hb0 : Hb1;
        const float*  ysrc = t ? (out + (size_t)(t - 1) * 2048) : y0;
        float*        yt   = out + (size_t)t * 2048;

        bar_wait(gctr, 32 * t);   // y_{t-1} + H from step t-1 visible

        // ---- stage1: X0 rows [rowbase,+8) = relu([x_t,y] @ W_in^T + b_in) --
        if (tid < 248) {
            XS[xr * 32 + xc] = xreg;
        } else if (tid < 256) {
            int rr2 = tid - 248;
            XS[rr2 * 32 + 31] = ysrc[rowbase + rr2];
            yt[rowbase + rr2] = bout0;            // init y with output bias
        }
        __syncthreads();
        {
            const int d = tid;
            const float bi = BIN[d];
            float a0[8];
#pragma unroll
            for (int rr2 = 0; rr2 < 8; ++rr2) a0[rr2] = bi;
#pragma unroll
            for (int k4 = 0; k4 < 8; ++k4) {
                const f32x4 w4 = *(const f32x4*)&WT4[k4 * 2048 + d * 4];
#pragma unroll
                for (int rr2 = 0; rr2 < 8; ++rr2) {
                    const f32x4 x4 = *(const f32x4*)&XS[rr2 * 32 + k4 * 4];
                    a0[rr2] += x4[0] * w4[0] + x4[1] * w4[1] + x4[2] * w4[2] + x4[3] * w4[3];
                }
            }
#pragma unroll
            for (int rr2 = 0; rr2 < 8; ++rr2)
                X0g[(size_t)(rowbase + rr2) * 512 + d] = (bf16_t)fmaxf(a0[rr2], 0.f);
        }
        bar_arrive(gctr);                          // -> 32t+16

        // prefetch next step's x slice while others finish stage1
        {
            const int tn = (t + 1 < SEQ) ? (t + 1) : t;
            if (tid < 248)
                xreg = x[(size_t)tn * (2048 * 31) + (size_t)(rowbase + xr) * 31 + xc];
        }
        bar_wait(gctr, 32 * t + 16);               // group's X0 complete

        // ---- stage2: gates GEMM (register-B, LDS-A, XOR bank swizzle) ----
        f32x4 acc[8][2];
#pragma unroll
        for (int mi = 0; mi < 8; ++mi)
#pragma unroll
            for (int ni = 0; ni < 2; ++ni) {
                f32x4 z = {0.f, 0.f, 0.f, 0.f};
                acc[mi][ni] = z;
            }
        const char* ASw = UNI + (wsl ? 16384 : 0);
#pragma unroll
        for (int kt = 0; kt < 8; ++kt) {
            const int lc = (l & 7) ^ ((l >> 3) & 7);
#pragma unroll
            for (int i = 0; i < 2; ++i) {
                const int rowl = i * 64 + w * 8 + (l >> 3);
                const size_t go = (size_t)(G * 128 + rowl) * 512 + kt * 64 + lc * 8;
                gload16(X0g + go, UNI + i * 8192 + w * 1024);          // As0 <- X0
                gload16(Hin + go, UNI + 16384 + i * 8192 + w * 1024);  // As1 <- H
            }
            __syncthreads();
#pragma unroll
            for (int c2 = 0; c2 < 2; ++c2) {
                bf16x8 af[8];
#pragma unroll
                for (int mi = 0; mi < 8; ++mi) {
                    const int row = mi * 16 + r;
                    const int ph  = (c2 * 4 + q) ^ (r & 7);
                    af[mi] = *(const bf16x8*)(ASw + row * 128 + ph * 16);
                }
#pragma unroll
                for (int mi = 0; mi < 8; ++mi)
#pragma unroll
                    for (int ni = 0; ni < 2; ++ni)
                        acc[mi][ni] = __builtin_amdgcn_mfma_f32_16x16x32_bf16(
                            af[mi], wfrag[kt * 2 + c2][ni], acc[mi][ni], 0, 0, 0);
            }
            __syncthreads();
        }

        // ---- epilogue: K-half reduce through LDS + fused LSTM cell ----
#pragma unroll
        for (int h = 0; h < 2; ++h) {
#pragma unroll
            for (int mi4 = 0; mi4 < 4; ++mi4) {
                const int mi = h * 4 + mi4;
#pragma unroll
                for (int ni = 0; ni < 2; ++ni)
#pragma unroll
                    for (int rr = 0; rr < 4; ++rr)
                        GS[wsl * GSPLANE + (mi4 * 16 + q * 4 + rr) * 129 + wn * 32 + ni * 16 + r]
                            = acc[mi][ni][rr];
            }
            __syncthreads();
            {
                const int bg2 = G * 128 + h * 64 + erow;
                const float* g0 = GS + erow * 129;
                const float* g1 = GS + GSPLANE + erow * 129;
                float ysum = 0.f;
                bf16x4v hv;
#pragma unroll
                for (int ii = 0; ii < 4; ++ii) {
                    const int dl = edg * 4 + ii;
                    const float gi = g0[dl]      + g1[dl]      + BGT[dl];
                    const float gf = g0[32 + dl] + g1[32 + dl] + BGT[32 + dl];
                    const float gg = g0[64 + dl] + g1[64 + dl] + BGT[64 + dl];
                    const float go = g0[96 + dl] + g1[96 + dl] + BGT[96 + dl];
                    const float cn = sigmoid_f(gf) * creg[h][ii] + sigmoid_f(gi) * tanh_f(gg);
                    creg[h][ii] = cn;
                    const float hval = sigmoid_f(go) * tanh_f(cn);
                    hv[ii] = (bf16_t)hval;
                    ysum += hval * WOUT[dl];
                }
                *(bf16x4v*)(Hout + (size_t)bg2 * 512 + m * 32 + edg * 4) = hv;
                ysum += __shfl_xor(ysum, 1);
                ysum += __shfl_xor(ysum, 2);
                ysum += __shfl_xor(ysum, 4);
                if (edg == 0) atomicAdd(yt + bg2, ysum);
            }
            __syncthreads();
        }
        bar_arrive(gctr);                          // -> 32t+32
    }
}

// ---------------------------------------------------------------------------
extern "C" void kernel_launch(void* const* d_in, const int* in_sizes, int n_in,
                              void* d_out, int out_size, void* d_ws, size_t ws_size,
                              hipStream_t stream) {
    const float* x     = (const float*)d_in[0];
    const float* h0    = (const float*)d_in[1];
    const float* c0    = (const float*)d_in[2];
    const float* y0    = (const float*)d_in[3];
    const float* W_in  = (const float*)d_in[4];
    const float* b_in  = (const float*)d_in[5];
    const float* W_ih  = (const float*)d_in[6];
    const float* W_hh  = (const float*)d_in[7];
    const float* b_ih  = (const float*)d_in[8];
    const float* b_hh  = (const float*)d_in[9];
    const float* W_out = (const float*)d_in[10];
    const float* b_out = (const float*)d_in[11];
    float* out = (float*)d_out;

    char* ws = (char*)d_ws;
    bf16_t* Wcat  = (bf16_t*)(ws);                  // 4 MiB
    bf16_t* X0    = (bf16_t*)(ws + (4u << 20));     // 2 MiB
    bf16_t* Hb0   = (bf16_t*)(ws + (6u << 20));     // 2 MiB
    bf16_t* Hb1   = (bf16_t*)(ws + (8u << 20));     // 2 MiB
    float*  bgate = (float*)(ws + (10u << 20));     // 8 KiB
    int*    ctrs  = (int*)(ws + (10u << 20) + 8192);// 544 ints

    prep_w   <<<2048, 256, 0, stream>>>(W_ih, W_hh, Wcat);
    prep_h0  <<<2048, 256, 0, stream>>>(h0, Hb0);
    prep_bias<<<8,    256, 0, stream>>>(b_ih, b_hh, bgate, ctrs);

    hipFuncSetAttribute((const void*)holstm_persist,
                        hipFuncAttributeMaxDynamicSharedMemorySize, SMEM_BYTES);
    void* kargs[] = {
        (void*)&x, (void*)&y0, (void*)&c0, (void*)&W_in, (void*)&b_in, (void*)&b_out,
        (void*)&W_out, (void*)&Wcat, (void*)&bgate, (void*)&X0, (void*)&Hb0, (void*)&Hb1,
        (void*)&out, (void*)&ctrs };
    hipError_t e = hipLaunchCooperativeKernel((const void*)holstm_persist,
                                              dim3(NBLK), dim3(512), kargs,
                                              SMEM_BYTES, stream);
    if (e != hipSuccess) {
        holstm_persist<<<NBLK, 512, SMEM_BYTES, stream>>>(
            x, y0, c0, W_in, b_in, b_out, W_out, Wcat, bgate, X0, Hb0, Hb1, out, ctrs);
    }
    (void)in_sizes; (void)n_in; (void)out_size; (void)ws_size;
}

// Round 4
// 22581.215 us; speedup vs baseline: 1.6155x; 1.4089x over previous
//
#include <hip/hip_runtime.h>
#include <hip/hip_bf16.h>
#include <stdint.h>

#define SEQ   512
#define NBLK  256

typedef __bf16 bf16_t;
typedef bf16_t bf16x8 __attribute__((ext_vector_type(8)));
typedef bf16_t bf16x4v __attribute__((ext_vector_type(4)));
typedef float  f32x4  __attribute__((ext_vector_type(4)));

// ---- dynamic LDS layout (bytes) ----
#define OFF_WT4   0        // W_in^T packed f32 [8][512][4] (64 KiB)
#define OFF_BIN   65536    // b_in f32[512]
#define OFF_BGT   67584    // b_gate strips for this member (4x32)
#define OFF_WOUT  68096    // W_out[m*32..+32]
#define OFF_XS    68224    // xs f32[8][32]; col 31 = y_prev
#define OFF_UNION 69632    // union{ As0+As1 (32 KiB) | Gs f32[2][64][129] (66 KiB) }
#define SMEM_BYTES 135680
#define GSPLANE   8256     // floats per Gs plane (64*129)

// ---- device-coherent (agent-scope, relaxed) accessors: lower to sc1 ops ----
// sc1 stores write through to the coherent point; sc1 loads read it (never a
// stale per-XCD L2 line). No buffer_wbl2 / buffer_inv anywhere -> L2 stays
// resident for weights and the x stream. Correct for ANY block->XCD placement.
__device__ __forceinline__ uint64_t cload64(const void* p) {
    return __hip_atomic_load((const uint64_t*)p, __ATOMIC_RELAXED, __HIP_MEMORY_SCOPE_AGENT);
}
__device__ __forceinline__ void cstore64(void* p, uint64_t v) {
    __hip_atomic_store((uint64_t*)p, v, __ATOMIC_RELAXED, __HIP_MEMORY_SCOPE_AGENT);
}
__device__ __forceinline__ void cstore32(void* p, uint32_t v) {
    __hip_atomic_store((uint32_t*)p, v, __ATOMIC_RELAXED, __HIP_MEMORY_SCOPE_AGENT);
}
__device__ __forceinline__ void cstoref(float* p, float v) {
    __hip_atomic_store(p, v, __ATOMIC_RELAXED, __HIP_MEMORY_SCOPE_AGENT);
}
__device__ __forceinline__ float cloadf(const float* p) {
    return __hip_atomic_load(p, __ATOMIC_RELAXED, __HIP_MEMORY_SCOPE_AGENT);
}

__device__ __forceinline__ float sigmoid_f(float x) { return 1.f / (1.f + __expf(-x)); }
__device__ __forceinline__ float tanh_f(float x)    { float e = __expf(2.f * x); return 1.f - 2.f / (e + 1.f); }

// group-local (16-block) split barrier; relaxed atomics, NO cache maintenance.
// __syncthreads() before the add drains vmcnt for all waves (sc1 stores are
// globally visible once retired); readers only use sc1 loads, so no acquire
// invalidate is needed.
__device__ __forceinline__ void bar_arrive(int* c) {
    __syncthreads();
    if (threadIdx.x == 0) {
        __builtin_amdgcn_s_waitcnt(0);
        __hip_atomic_fetch_add(c, 1, __ATOMIC_RELAXED, __HIP_MEMORY_SCOPE_AGENT);
    }
}
__device__ __forceinline__ void bar_wait(int* c, int target) {
    if (threadIdx.x == 0) {
        while (__hip_atomic_load(c, __ATOMIC_RELAXED, __HIP_MEMORY_SCOPE_AGENT) < target)
            __builtin_amdgcn_s_sleep(1);
    }
    __syncthreads();
}

// ---------------- prep kernels ----------------
__global__ void prep_w(const float* __restrict__ W_ih, const float* __restrict__ W_hh,
                       bf16_t* __restrict__ Wcat) {
    const int j = blockIdx.x;
    for (int k = threadIdx.x; k < 1024; k += 256) {
        float v = (k < 512) ? W_ih[(size_t)j * 512 + k] : W_hh[(size_t)j * 512 + (k - 512)];
        Wcat[(size_t)j * 1024 + k] = (bf16_t)v;
    }
}
__global__ void prep_h0(const float* __restrict__ h0, bf16_t* __restrict__ H0) {
    const int b = blockIdx.x;
    for (int d = threadIdx.x; d < 512; d += 256)
        H0[(size_t)b * 512 + d] = (bf16_t)h0[(size_t)b * 512 + d];
}
__global__ void prep_bias(const float* __restrict__ b_ih, const float* __restrict__ b_hh,
                          float* __restrict__ bg, int* __restrict__ ctrs) {
    int j = blockIdx.x * 256 + threadIdx.x;
    bg[j] = b_ih[j] + b_hh[j];
    if (j < 544) ctrs[j] = 0;
}

// ---------------- persistent whole-sequence kernel ----------------
// group G = bid&15 owns batch rows [G*128,+128); member m = bid>>4 owns
// d-strip [m*32,+32) x 4 gates. All cross-block traffic via sc1 (coherent
// point); weights + x stream stay cached in L2.
__global__ __launch_bounds__(512, 2) void holstm_persist(
    const float* __restrict__ x,     const float* __restrict__ y0,
    const float* __restrict__ c0,    const float* __restrict__ W_in,
    const float* __restrict__ b_in,  const float* __restrict__ b_out,
    const float* __restrict__ W_out, const bf16_t* __restrict__ Wcat,
    const float* __restrict__ bgate, bf16_t* __restrict__ X0g,
    bf16_t* __restrict__ Hb0,        bf16_t* __restrict__ Hb1,
    float* __restrict__ out,         int* __restrict__ ctrs)
{
    extern __shared__ char smem[];
    float* WT4  = (float*)(smem + OFF_WT4);
    float* BIN  = (float*)(smem + OFF_BIN);
    float* BGT  = (float*)(smem + OFF_BGT);
    float* WOUT = (float*)(smem + OFF_WOUT);
    float* XS   = (float*)(smem + OFF_XS);
    char*  UNI  = smem + OFF_UNION;
    float* GS   = (float*)UNI;

    const int tid = threadIdx.x;
    const int l   = tid & 63;
    const int w   = tid >> 6;
    const int r   = l & 15;
    const int q   = l >> 4;
    const int wn  = w & 3;       // gate strip
    const int wsl = w >> 2;      // K-half select
    const int bid = blockIdx.x;
    const int G   = bid & 15;    // group (batch slice)
    const int m   = bid >> 4;    // member (d-strip)
    int* gctr = ctrs + G * 32;

    // one-time LDS staging
    for (int i = tid; i < 16384; i += 512) {
        int k = i & 31, d = i >> 5;
        WT4[(k >> 2) * 2048 + d * 4 + (k & 3)] = W_in[i];
    }
    BIN[tid] = b_in[tid];
    if (tid < 128) BGT[tid]  = bgate[(tid >> 5) * 512 + m * 32 + (tid & 31)];
    if (tid < 32)  WOUT[tid] = W_out[m * 32 + tid];

    // one-time register weight fragments: N=32 cols (ni*16+r), K-half wsl
    bf16x8 wfrag[16][2];
#pragma unroll
    for (int c = 0; c < 16; ++c)
#pragma unroll
        for (int ni = 0; ni < 2; ++ni) {
            const int j = wn * 512 + m * 32 + ni * 16 + r;
            const int k = wsl * 512 + c * 32 + q * 8;
            wfrag[c][ni] = *(const bf16x8*)(Wcat + (size_t)j * 1024 + k);
        }

    // persistent cell state (registers)
    const int erow = tid >> 3, edg = tid & 7;
    float creg[2][4];
#pragma unroll
    for (int h = 0; h < 2; ++h) {
        const int bg2 = G * 128 + h * 64 + erow;
#pragma unroll
        for (int ii = 0; ii < 4; ++ii)
            creg[h][ii] = c0[(size_t)bg2 * 512 + m * 32 + edg * 4 + ii];
    }
    const float bout0 = b_out[0];
    const int rowbase = G * 128 + m * 8;       // this member's stage-1 rows
    const int xr = tid / 31, xc = tid - xr * 31;

    // prefetch x for t=0 (read-only input: plain cached load)
    float xreg = 0.f;
    if (tid < 248)
        xreg = x[(size_t)(rowbase + xr) * 31 + xc];
    __syncthreads();

    for (int t = 0; t < SEQ; ++t) {
        const bf16_t* Hin  = (t & 1) ? Hb1 : Hb0;
        bf16_t*       Hout = (t & 1) ? Hb0 : Hb1;
        const float*  ysrc = t ? (out + (size_t)(t - 1) * 2048) : y0;
        float*        yt   = out + (size_t)t * 2048;

        bar_wait(gctr, 32 * t);   // y_{t-1} + H from step t-1 visible

        // ---- stage1: X0 rows [rowbase,+8) = relu([x_t,y] @ W_in^T + b_in) --
        if (tid < 248) {
            XS[xr * 32 + xc] = xreg;
        } else if (tid < 256) {
            int rr2 = tid - 248;
            XS[rr2 * 32 + 31] = t ? cloadf(ysrc + rowbase + rr2) : ysrc[rowbase + rr2];
            cstoref(yt + rowbase + rr2, bout0);   // init y with output bias
        }
        __syncthreads();
        {
            const int d = tid;
            const float bi = BIN[d];
            float a0[8];
#pragma unroll
            for (int rr2 = 0; rr2 < 8; ++rr2) a0[rr2] = bi;
#pragma unroll
            for (int k4 = 0; k4 < 8; ++k4) {
                const f32x4 w4 = *(const f32x4*)&WT4[k4 * 2048 + d * 4];
#pragma unroll
                for (int rr2 = 0; rr2 < 8; ++rr2) {
                    const f32x4 x4 = *(const f32x4*)&XS[rr2 * 32 + k4 * 4];
                    a0[rr2] += x4[0] * w4[0] + x4[1] * w4[1] + x4[2] * w4[2] + x4[3] * w4[3];
                }
            }
            // pack (d, d+1) pairs across adjacent lanes -> coherent 4B stores
#pragma unroll
            for (int rr2 = 0; rr2 < 8; ++rr2) {
                float v = fmaxf(a0[rr2], 0.f);
                float o = __shfl_xor(v, 1);
                if ((tid & 1) == 0) {
                    union { struct { bf16_t lo, hi; } s; uint32_t u; } pk;
                    pk.s.lo = (bf16_t)v; pk.s.hi = (bf16_t)o;
                    cstore32(&X0g[(size_t)(rowbase + rr2) * 512 + d], pk.u);
                }
            }
        }
        bar_arrive(gctr);                          // -> 32t+16

        // prefetch next step's x slice while others finish stage1
        {
            const int tn = (t + 1 < SEQ) ? (t + 1) : t;
            if (tid < 248)
                xreg = x[(size_t)tn * (2048 * 31) + (size_t)(rowbase + xr) * 31 + xc];
        }
        bar_wait(gctr, 32 * t + 16);               // group's X0 complete

        // ---- stage2: gates GEMM (register-B, LDS-A, XOR bank swizzle) ----
        f32x4 acc[8][2];
#pragma unroll
        for (int mi = 0; mi < 8; ++mi)
#pragma unroll
            for (int ni = 0; ni < 2; ++ni) {
                f32x4 z = {0.f, 0.f, 0.f, 0.f};
                acc[mi][ni] = z;
            }
        const char* ASw = UNI + (wsl ? 16384 : 0);
#pragma unroll
        for (int kt = 0; kt < 8; ++kt) {
            const int lc = (l & 7) ^ ((l >> 3) & 7);
#pragma unroll
            for (int i = 0; i < 2; ++i) {
                const int rowl = i * 64 + w * 8 + (l >> 3);
                const size_t go = (size_t)(G * 128 + rowl) * 512 + kt * 64 + lc * 8;
                const uint64_t xa = cload64(X0g + go);
                const uint64_t xb = cload64(X0g + go + 4);
                const uint64_t ha = cload64(Hin + go);
                const uint64_t hb = cload64(Hin + go + 4);
                uint64_t* d0 = (uint64_t*)(UNI + i * 8192 + w * 1024 + l * 16);
                d0[0] = xa; d0[1] = xb;
                uint64_t* d1 = (uint64_t*)(UNI + 16384 + i * 8192 + w * 1024 + l * 16);
                d1[0] = ha; d1[1] = hb;
            }
            __syncthreads();
#pragma unroll
            for (int c2 = 0; c2 < 2; ++c2) {
                bf16x8 af[8];
#pragma unroll
                for (int mi = 0; mi < 8; ++mi) {
                    const int row = mi * 16 + r;
                    const int ph  = (c2 * 4 + q) ^ (r & 7);
                    af[mi] = *(const bf16x8*)(ASw + row * 128 + ph * 16);
                }
#pragma unroll
                for (int mi = 0; mi < 8; ++mi)
#pragma unroll
                    for (int ni = 0; ni < 2; ++ni)
                        acc[mi][ni] = __builtin_amdgcn_mfma_f32_16x16x32_bf16(
                            af[mi], wfrag[kt * 2 + c2][ni], acc[mi][ni], 0, 0, 0);
            }
            __syncthreads();
        }

        // ---- epilogue: K-half reduce through LDS + fused LSTM cell ----
#pragma unroll
        for (int h = 0; h < 2; ++h) {
#pragma unroll
            for (int mi4 = 0; mi4 < 4; ++mi4) {
                const int mi = h * 4 + mi4;
#pragma unroll
                for (int ni = 0; ni < 2; ++ni)
#pragma unroll
                    for (int rr = 0; rr < 4; ++rr)
                        GS[wsl * GSPLANE + (mi4 * 16 + q * 4 + rr) * 129 + wn * 32 + ni * 16 + r]
                            = acc[mi][ni][rr];
            }
            __syncthreads();
            {
                const int bg2 = G * 128 + h * 64 + erow;
                const float* g0 = GS + erow * 129;
                const float* g1 = GS + GSPLANE + erow * 129;
                float ysum = 0.f;
                union { bf16x4v v; uint64_t u; } hu;
#pragma unroll
                for (int ii = 0; ii < 4; ++ii) {
                    const int dl = edg * 4 + ii;
                    const float gi = g0[dl]      + g1[dl]      + BGT[dl];
                    const float gf = g0[32 + dl] + g1[32 + dl] + BGT[32 + dl];
                    const float gg = g0[64 + dl] + g1[64 + dl] + BGT[64 + dl];
                    const float go = g0[96 + dl] + g1[96 + dl] + BGT[96 + dl];
                    const float cn = sigmoid_f(gf) * creg[h][ii] + sigmoid_f(gi) * tanh_f(gg);
                    creg[h][ii] = cn;
                    const float hval = sigmoid_f(go) * tanh_f(cn);
                    hu.v[ii] = (bf16_t)hval;
                    ysum += hval * WOUT[dl];
                }
                cstore64(Hout + (size_t)bg2 * 512 + m * 32 + edg * 4, hu.u);
                ysum += __shfl_xor(ysum, 1);
                ysum += __shfl_xor(ysum, 2);
                ysum += __shfl_xor(ysum, 4);
                if (edg == 0) atomicAdd(yt + bg2, ysum);
            }
            __syncthreads();
        }
        bar_arrive(gctr);                          // -> 32t+32
    }
}

// ---------------------------------------------------------------------------
extern "C" void kernel_launch(void* const* d_in, const int* in_sizes, int n_in,
                              void* d_out, int out_size, void* d_ws, size_t ws_size,
                              hipStream_t stream) {
    const float* x     = (const float*)d_in[0];
    const float* h0    = (const float*)d_in[1];
    const float* c0    = (const float*)d_in[2];
    const float* y0    = (const float*)d_in[3];
    const float* W_in  = (const float*)d_in[4];
    const float* b_in  = (const float*)d_in[5];
    const float* W_ih  = (const float*)d_in[6];
    const float* W_hh  = (const float*)d_in[7];
    const float* b_ih  = (const float*)d_in[8];
    const float* b_hh  = (const float*)d_in[9];
    const float* W_out = (const float*)d_in[10];
    const float* b_out = (const float*)d_in[11];
    float* out = (float*)d_out;

    char* ws = (char*)d_ws;
    bf16_t* Wcat  = (bf16_t*)(ws);                  // 4 MiB
    bf16_t* X0    = (bf16_t*)(ws + (4u << 20));     // 2 MiB
    bf16_t* Hb0   = (bf16_t*)(ws + (6u << 20));     // 2 MiB
    bf16_t* Hb1   = (bf16_t*)(ws + (8u << 20));     // 2 MiB
    float*  bgate = (float*)(ws + (10u << 20));     // 8 KiB
    int*    ctrs  = (int*)(ws + (10u << 20) + 8192);// 544 ints

    prep_w   <<<2048, 256, 0, stream>>>(W_ih, W_hh, Wcat);
    prep_h0  <<<2048, 256, 0, stream>>>(h0, Hb0);
    prep_bias<<<8,    256, 0, stream>>>(b_ih, b_hh, bgate, ctrs);

    hipFuncSetAttribute((const void*)holstm_persist,
                        hipFuncAttributeMaxDynamicSharedMemorySize, SMEM_BYTES);
    void* kargs[] = {
        (void*)&x, (void*)&y0, (void*)&c0, (void*)&W_in, (void*)&b_in, (void*)&b_out,
        (void*)&W_out, (void*)&Wcat, (void*)&bgate, (void*)&X0, (void*)&Hb0, (void*)&Hb1,
        (void*)&out, (void*)&ctrs };
    hipError_t e = hipLaunchCooperativeKernel((const void*)holstm_persist,
                                              dim3(NBLK), dim3(512), kargs,
                                              SMEM_BYTES, stream);
    if (e != hipSuccess) {
        holstm_persist<<<NBLK, 512, SMEM_BYTES, stream>>>(
            x, y0, c0, W_in, b_in, b_out, W_out, Wcat, bgate, X0, Hb0, Hb1, out, ctrs);
    }
    (void)in_sizes; (void)n_in; (void)out_size; (void)ws_size;
}